// Round 1
// baseline (322.340 us; speedup 1.0000x reference)
//
#include <hip/hip_runtime.h>
#include <stdint.h>

typedef unsigned short u16;
typedef __attribute__((ext_vector_type(8))) short bf16x8;   // 8 bf16 = 4 VGPRs
typedef __attribute__((ext_vector_type(4))) float f32x4;

#define MFMA16(a, b, c) __builtin_amdgcn_mfma_f32_16x16x32_bf16((a), (b), (c), 0, 0, 0)
#define GLD16(gp, lp) __builtin_amdgcn_global_load_lds( \
    (__attribute__((address_space(1))) void*)(gp), \
    (__attribute__((address_space(3))) void*)(lp), 16, 0, 0)

__device__ __forceinline__ u16 f2b(float f) {   // fp32 -> bf16 RNE
  uint32_t u = __float_as_uint(f);
  u += 0x7FFFu + ((u >> 16) & 1u);
  return (u16)(u >> 16);
}
__device__ __forceinline__ float tanhfast(float x) {
  float e = __expf(2.f * x);
  return (e - 1.f) / (e + 1.f);
}

// ---------------- workspace layout (bytes) ----------------
// h1 bf16 [8192][12][12][16]        @ 0          37,748,736
// feat bf16 [8192][3200]            @ 37748736   52,428,800
// W1T bf16 [5][128][3200]           @ 90177536    4,096,000
// W2T bf16 [5][128][128]            @ 94273536      163,840
// W2colF bf16 [5][2][64][8]         @ 94437376       10,240
// WcatT bf16 [16][3200]             @ 94447616      102,400
// rw f32 [8192][5]                  @ 94550016      163,840
// moe f32 [8192][128]               @ 94713856    4,194,304   (total ~98.9 MB)

// ============ prep: weight repack/transpose to bf16 ============
__global__ __launch_bounds__(256) void prep_kernel(
    const float* __restrict__ c2w, const float* __restrict__ Wg,
    const float* __restrict__ Wglu, const float* __restrict__ W1e,
    const float* __restrict__ W2e, u16* __restrict__ W2colF,
    u16* __restrict__ WcatT, u16* __restrict__ W1T, u16* __restrict__ W2T) {
  int i = blockIdx.x * 256 + threadIdx.x;
  if (i < 5120) {                       // conv2 B-fragments, k=(ky*3+kx)*16+ci, pad->160
    int j = i & 7, l = (i >> 3) & 63, nt = (i >> 9) & 1, s = i >> 10;
    int k = s * 32 + ((l >> 4) & 3) * 8 + j;
    int n = (l & 15) + nt * 16;
    float v = 0.f;
    if (k < 144) {
      int kykx = k >> 4, ci = k & 15;
      int ky = kykx / 3, kx = kykx - ky * 3;
      v = c2w[((n * 16 + ci) * 3 + ky) * 3 + kx];
    }
    W2colF[i] = f2b(v);
  } else if (i < 56320) {               // WcatT[16][3200]
    int o = i - 5120;
    int r = o / 3200, d = o - r * 3200;
    float v = 0.f;
    if (r < 5) v = Wg[d * 5 + r];
    else if (r < 10) v = Wglu[d * 5 + (r - 5)];
    WcatT[o] = f2b(v);
  } else if (i < 2104320) {             // W1T[e][h][d]
    int o = i - 56320;
    int e = o / 409600, rem = o - e * 409600;
    int h = rem / 3200, d = rem - h * 3200;
    W1T[o] = f2b(W1e[(e * 3200 + d) * 128 + h]);
  } else if (i < 2186240) {             // W2T[e][g][h]
    int o = i - 2104320;
    int e = o >> 14, rem = o & 16383;
    int g = rem >> 7, h = rem & 127;
    W2T[o] = f2b(W2e[(e * 128 + h) * 128 + g]);
  }
}

// ============ conv1 + relu + maxpool2 -> h1 bf16 HWC ============
__global__ __launch_bounds__(192) void conv1_kernel(
    const float* __restrict__ x, const float* __restrict__ w1,
    const float* __restrict__ b1, u16* __restrict__ h1) {
  __shared__ float xs[784];
  __shared__ float wsh[400];
  __shared__ float bsh[16];
  int t = threadIdx.x, b = blockIdx.x;
  const float4* xg = (const float4*)(x + (size_t)b * 784);
  float4* xs4 = (float4*)xs;
  for (int i = t; i < 196; i += 192) xs4[i] = xg[i];
  for (int i = t; i < 400; i += 192) wsh[i] = w1[i];
  if (t < 16) bsh[t] = b1[t];
  __syncthreads();
  int oc = t & 15, q0 = t >> 4;
  float w[25];
#pragma unroll
  for (int k = 0; k < 25; k++) w[k] = wsh[oc * 25 + k];
  float bias = bsh[oc];
  u16* out = h1 + (size_t)b * 2304;
#pragma unroll
  for (int it = 0; it < 6; it++) {
    int q = q0 + 12 * it;           // 0..71
    int py = q / 6, px2 = q - py * 6;
    int y0 = 2 * py, x0 = 4 * px2;
    float win[6][8];
#pragma unroll
    for (int r = 0; r < 6; r++) {
      const float4* p = (const float4*)&xs[(y0 + r) * 28 + x0];
      float4 a = p[0], c = p[1];
      win[r][0] = a.x; win[r][1] = a.y; win[r][2] = a.z; win[r][3] = a.w;
      win[r][4] = c.x; win[r][5] = c.y; win[r][6] = c.z; win[r][7] = c.w;
    }
#pragma unroll
    for (int half = 0; half < 2; half++) {
      int dxb = 2 * half;
      float c00 = 0.f, c01 = 0.f, c10 = 0.f, c11 = 0.f;
#pragma unroll
      for (int ky = 0; ky < 5; ky++)
#pragma unroll
        for (int kx = 0; kx < 5; kx++) {
          float wv = w[ky * 5 + kx];
          c00 += wv * win[ky][dxb + kx];
          c01 += wv * win[ky][dxb + kx + 1];
          c10 += wv * win[ky + 1][dxb + kx];
          c11 += wv * win[ky + 1][dxb + kx + 1];
        }
      float m = fmaxf(fmaxf(c00, c01), fmaxf(c10, c11)) + bias;
      m = fmaxf(m, 0.f);
      int px = 2 * px2 + half;
      out[(py * 12 + px) * 16 + oc] = f2b(m);
    }
  }
}

// ============ conv2 implicit-GEMM MFMA -> feat bf16 [B][3200] ============
__global__ __launch_bounds__(256) void conv2_kernel(
    const u16* __restrict__ h1, const u16* __restrict__ W2colF,
    const float* __restrict__ b2, u16* __restrict__ feat) {
  int t = threadIdx.x;
  int w = t >> 6, l = t & 63;
  bf16x8 bfr[5][2];
#pragma unroll
  for (int s = 0; s < 5; s++)
#pragma unroll
    for (int nt = 0; nt < 2; nt++)
      bfr[s][nt] = *(const bf16x8*)(W2colF + ((size_t)(s * 2 + nt) * 64 + l) * 8);
  int lm = l & 15, lq = l >> 4, hi = l >> 5;
  int cib = (lq & 1) * 8;
  int g0 = blockIdx.x * 128 + w * 32;
#pragma unroll
  for (int sub = 0; sub < 2; sub++) {
    int g = g0 + sub * 16 + lm;
    uint32_t bimg = (uint32_t)(((uint64_t)(uint32_t)g * 1374389535ull) >> 37);  // g/100
    int p = g - (int)bimg * 100;
    int y = (p * 205) >> 11;          // p/10
    int xc = p - y * 10;
    const u16* base = h1 + (size_t)bimg * 2304;
    f32x4 acc0 = {0.f, 0.f, 0.f, 0.f}, acc1 = {0.f, 0.f, 0.f, 0.f};
#pragma unroll
    for (int s = 0; s < 5; s++) {
      int kk = 2 * s + hi;
      if (kk > 8) kk = 8;            // pad lanes: B-frag rows there are zero
      int ky = (kk * 11) >> 5;       // kk/3 for kk<=8
      int kx = kk - ky * 3;
      int off = ((y + ky) * 12 + (xc + kx)) * 16 + cib;
      bf16x8 a = *(const bf16x8*)(base + off);
      acc0 = MFMA16(a, bfr[s][0], acc0);
      acc1 = MFMA16(a, bfr[s][1], acc1);
    }
#pragma unroll
    for (int nt = 0; nt < 2; nt++) {
      int n = lm + nt * 16;
      float bias = b2[n];
      f32x4 acc = nt ? acc1 : acc0;
#pragma unroll
      for (int rr = 0; rr < 4; rr++) {
        int gg = g0 + sub * 16 + lq * 4 + rr;
        uint32_t bi2 = (uint32_t)(((uint64_t)(uint32_t)gg * 1374389535ull) >> 37);
        int pp = gg - (int)bi2 * 100;
        float v = fmaxf(acc[rr] + bias, 0.f);
        feat[(size_t)bi2 * 3200 + n * 100 + pp] = f2b(v);
      }
    }
  }
}

// ============ router: GLU gates + top3 softmax -> rw[B][5] ============
__global__ __launch_bounds__(256) void router_kernel(
    const u16* __restrict__ feat, const u16* __restrict__ WcatT,
    const float* __restrict__ bg, const float* __restrict__ bglu,
    float* __restrict__ rw) {
  __shared__ float lg[64][16];
  int t = threadIdx.x, w = t >> 6, l = t & 63;
  int lm = l & 15, lq = l >> 4;
  int r0 = blockIdx.x * 64 + w * 16;
  const u16* arow = feat + (size_t)(r0 + lm) * 3200;
  const u16* brow = WcatT + (size_t)lm * 3200;
  f32x4 acc = {0.f, 0.f, 0.f, 0.f};
  for (int s = 0; s < 100; s++) {
    bf16x8 a = *(const bf16x8*)(arow + s * 32 + lq * 8);
    bf16x8 bb = *(const bf16x8*)(brow + s * 32 + lq * 8);
    acc = MFMA16(a, bb, acc);
  }
#pragma unroll
  for (int rr = 0; rr < 4; rr++) lg[w * 16 + lq * 4 + rr][lm] = acc[rr];
  __syncthreads();
  if (t < 64) {
    int b = blockIdx.x * 64 + t;
    float gt[5];
#pragma unroll
    for (int e = 0; e < 5; e++) {
      float va = lg[t][e] + bg[e];
      float vb = lg[t][5 + e] + bglu[e];
      gt[e] = va * (1.f / (1.f + __expf(-vb)));
    }
    float w3[3]; int i3[3];
    unsigned used = 0;
#pragma unroll
    for (int k = 0; k < 3; k++) {
      float best = -1e30f; int bi = 0;
#pragma unroll
      for (int e = 0; e < 5; e++)
        if (!((used >> e) & 1u) && gt[e] > best) { best = gt[e]; bi = e; }
      used |= 1u << bi; w3[k] = best; i3[k] = bi;
    }
    float s0 = __expf(w3[0] - w3[0]), s1 = __expf(w3[1] - w3[0]), s2 = __expf(w3[2] - w3[0]);
    float inv = 1.f / (s0 + s1 + s2);
    float o[5] = {0.f, 0.f, 0.f, 0.f, 0.f};
    o[i3[0]] = s0 * inv; o[i3[1]] = s1 * inv; o[i3[2]] = s2 * inv;
#pragma unroll
    for (int e = 0; e < 5; e++) rw[b * 5 + e] = o[e];
  }
}

// ============ experts: e1=tanh(feat@W1)+e2=tanh(e1@W2), weighted atomic combine ============
__global__ __launch_bounds__(256, 2) void expert_kernel(
    const u16* __restrict__ feat, const u16* __restrict__ W1T,
    const u16* __restrict__ W2T, const float* __restrict__ b1e,
    const float* __restrict__ b2e, const float* __restrict__ rw,
    float* __restrict__ moe) {
  __shared__ char lds[34816];
  u16* As = (u16*)lds;            // [128][32] bf16, rows of 64 B
  u16* Bs = (u16*)(lds + 8192);   // [128][32]
  u16* E1 = (u16*)lds;            // reuse: [128][136] bf16 (pad 8)
  int t = threadIdx.x, w = t >> 6, l = t & 63;
  int e = blockIdx.x % 5;
  int mt = blockIdx.x / 5;
  size_t m0 = (size_t)mt * 128;
  int lm = l & 15, lq = l >> 4;
  int m_off = (w & 1) * 64, n_off = (w >> 1) * 64;
  f32x4 acc[4][4] = {};
  const u16* aG = feat + (m0 + w * 32 + (l >> 2)) * 3200 + (l & 3) * 8;
  const u16* bG = W1T + (size_t)e * 409600 + (size_t)(w * 32 + (l >> 2)) * 3200 + (l & 3) * 8;
  u16* aL = As + w * 1024;        // wave-uniform LDS base; HW adds lane*16B
  u16* bL = Bs + w * 1024;
  for (int s = 0; s < 100; s++) {
    GLD16(aG, aL);
    GLD16(aG + 51200, aL + 512);
    GLD16(bG, bL);
    GLD16(bG + 51200, bL + 512);
    aG += 32; bG += 32;
    __syncthreads();
    bf16x8 af[4], bf[4];
#pragma unroll
    for (int i = 0; i < 4; i++) {
      af[i] = *(const bf16x8*)(As + (m_off + 16 * i + lm) * 32 + lq * 8);
      bf[i] = *(const bf16x8*)(Bs + (n_off + 16 * i + lm) * 32 + lq * 8);
    }
#pragma unroll
    for (int i = 0; i < 4; i++)
#pragma unroll
      for (int j = 0; j < 4; j++)
        acc[i][j] = MFMA16(af[i], bf[j], acc[i][j]);
    __syncthreads();
  }
  // e1 = tanh(acc + b1) -> LDS (bf16, [128][136])
  float bias1[4];
#pragma unroll
  for (int j = 0; j < 4; j++) bias1[j] = b1e[e * 128 + n_off + 16 * j + lm];
#pragma unroll
  for (int i = 0; i < 4; i++)
#pragma unroll
    for (int j = 0; j < 4; j++)
#pragma unroll
      for (int rr = 0; rr < 4; rr++) {
        float v = tanhfast(acc[i][j][rr] + bias1[j]);
        int row = m_off + 16 * i + lq * 4 + rr;
        int col = n_off + 16 * j + lm;
        E1[row * 136 + col] = f2b(v);
      }
  __syncthreads();
  // GEMM2: e2 = tanh(e1 @ W2T^T + b2)
  f32x4 acc2[4][4] = {};
  const u16* w2b = W2T + (size_t)e * 16384;
#pragma unroll
  for (int s = 0; s < 4; s++) {
    bf16x8 a2[4], b2f[4];
#pragma unroll
    for (int i = 0; i < 4; i++) {
      a2[i] = *(const bf16x8*)(E1 + (m_off + 16 * i + lm) * 136 + s * 32 + lq * 8);
      b2f[i] = *(const bf16x8*)(w2b + (n_off + 16 * i + lm) * 128 + s * 32 + lq * 8);
    }
#pragma unroll
    for (int i = 0; i < 4; i++)
#pragma unroll
      for (int j = 0; j < 4; j++)
        acc2[i][j] = MFMA16(a2[i], b2f[j], acc2[i][j]);
  }
  float bias2[4];
#pragma unroll
  for (int j = 0; j < 4; j++) bias2[j] = b2e[e * 128 + n_off + 16 * j + lm];
#pragma unroll
  for (int i = 0; i < 4; i++) {
    float wgt[4];
#pragma unroll
    for (int rr = 0; rr < 4; rr++)
      wgt[rr] = rw[(m0 + m_off + 16 * i + lq * 4 + rr) * 5 + e];
#pragma unroll
    for (int j = 0; j < 4; j++)
#pragma unroll
      for (int rr = 0; rr < 4; rr++) {
        float v = tanhfast(acc2[i][j][rr] + bias2[j]);
        int row = m_off + 16 * i + lq * 4 + rr;
        int col = n_off + 16 * j + lm;
        atomicAdd(&moe[(m0 + row) * 128 + col], wgt[rr] * v);
      }
  }
}

// ============ head: logits = moe@Ws+bs, softmax ============
__global__ __launch_bounds__(256) void head_kernel(
    const float* __restrict__ moe, const float* __restrict__ Ws,
    const float* __restrict__ bs, float* __restrict__ out) {
  int t = threadIdx.x, w = t >> 6, l = t & 63;
  int b = blockIdx.x * 4 + w;
  float2 mv = *(const float2*)(moe + (size_t)b * 128 + l * 2);
  const float* wr = Ws + (l * 2) * 10;
  float lg[10];
#pragma unroll
  for (int c = 0; c < 10; c++) lg[c] = mv.x * wr[c] + mv.y * wr[c + 10];
#pragma unroll
  for (int off = 32; off >= 1; off >>= 1)
#pragma unroll
    for (int c = 0; c < 10; c++) lg[c] += __shfl_xor(lg[c], off);
  float mx = -1e30f;
#pragma unroll
  for (int c = 0; c < 10; c++) { lg[c] += bs[c]; mx = fmaxf(mx, lg[c]); }
  float sum = 0.f;
#pragma unroll
  for (int c = 0; c < 10; c++) { lg[c] = __expf(lg[c] - mx); sum += lg[c]; }
  float inv = 1.f / sum;
  if (l < 10) out[(size_t)b * 10 + l] = lg[l] * inv;
}

extern "C" void kernel_launch(void* const* d_in, const int* in_sizes, int n_in,
                              void* d_out, int out_size, void* d_ws, size_t ws_size,
                              hipStream_t stream) {
  const float* x    = (const float*)d_in[0];
  const float* c1w  = (const float*)d_in[1];
  const float* c1b  = (const float*)d_in[2];
  const float* c2w  = (const float*)d_in[3];
  const float* c2b  = (const float*)d_in[4];
  const float* Wg   = (const float*)d_in[5];
  const float* bg   = (const float*)d_in[6];
  const float* Wglu = (const float*)d_in[7];
  const float* bglu = (const float*)d_in[8];
  const float* W1e  = (const float*)d_in[9];
  const float* b1e  = (const float*)d_in[10];
  const float* W2e  = (const float*)d_in[11];
  const float* b2e  = (const float*)d_in[12];
  const float* Wsp  = (const float*)d_in[13];
  const float* bsp  = (const float*)d_in[14];
  char* ws = (char*)d_ws;
  u16* h1     = (u16*)(ws + 0);
  u16* feat   = (u16*)(ws + 37748736);
  u16* W1T    = (u16*)(ws + 90177536);
  u16* W2T    = (u16*)(ws + 94273536);
  u16* W2colF = (u16*)(ws + 94437376);
  u16* WcatT  = (u16*)(ws + 94447616);
  float* rw   = (float*)(ws + 94550016);
  float* moe  = (float*)(ws + 94713856);

  hipMemsetAsync(moe, 0, (size_t)8192 * 128 * 4, stream);
  prep_kernel<<<8540, 256, 0, stream>>>(c2w, Wg, Wglu, W1e, W2e, W2colF, WcatT, W1T, W2T);
  conv1_kernel<<<8192, 192, 0, stream>>>(x, c1w, c1b, h1);
  conv2_kernel<<<6400, 256, 0, stream>>>(h1, W2colF, c2b, feat);
  router_kernel<<<128, 256, 0, stream>>>(feat, WcatT, bg, bglu, rw);
  expert_kernel<<<320, 256, 0, stream>>>(feat, W1T, W2T, b1e, b2e, rw, moe);
  head_kernel<<<2048, 256, 0, stream>>>(moe, Wsp, bsp, (float*)d_out);
}

// Round 2
// 306.440 us; speedup vs baseline: 1.0519x; 1.0519x over previous
//
#include <hip/hip_runtime.h>
#include <stdint.h>

typedef unsigned short u16;
typedef __attribute__((ext_vector_type(8))) short bf16x8;   // 8 bf16 = 4 VGPRs
typedef __attribute__((ext_vector_type(4))) float f32x4;

#define MFMA16(a, b, c) __builtin_amdgcn_mfma_f32_16x16x32_bf16((a), (b), (c), 0, 0, 0)
#define GLD16(gp, lp) __builtin_amdgcn_global_load_lds( \
    (__attribute__((address_space(1))) void*)(gp), \
    (__attribute__((address_space(3))) void*)(lp), 16, 0, 0)

__device__ __forceinline__ u16 f2b(float f) {   // fp32 -> bf16 RNE
  uint32_t u = __float_as_uint(f);
  u += 0x7FFFu + ((u >> 16) & 1u);
  return (u16)(u >> 16);
}
__device__ __forceinline__ float tanhfast(float x) {
  float e = __expf(2.f * x);
  return (e - 1.f) / (e + 1.f);
}

// ---------------- workspace layout (bytes) ----------------
// region0: h1 bf16 [8192][12][12][16]  @ 0         37,748,736
//          e1acc f32 [8192][640] overlays region0 (h1 dead after conv2)
// feat bf16 [8192][3200]            @ 37748736   52,428,800
// W1T bf16 [5][128][3200]           @ 90177536    4,096,000
// W2T bf16 [5][128][128]            @ 94273536      163,840
// W2colF bf16 [5][2][64][8]         @ 94437376       10,240
// WcatT bf16 [16][3200]             @ 94447616      102,400
// rw f32 [8192][5]                  @ 94550016      163,840   (total 94.7 MB)

// ============ prep_misc: small weight repacks ============
__global__ __launch_bounds__(256) void prep_misc_kernel(
    const float* __restrict__ c2w, const float* __restrict__ Wg,
    const float* __restrict__ Wglu, const float* __restrict__ W2e,
    u16* __restrict__ W2colF, u16* __restrict__ WcatT, u16* __restrict__ W2T) {
  int i = blockIdx.x * 256 + threadIdx.x;
  if (i < 5120) {                       // conv2 B-fragments, k=(ky*3+kx)*16+ci, pad->160
    int j = i & 7, l = (i >> 3) & 63, nt = (i >> 9) & 1, s = i >> 10;
    int k = s * 32 + ((l >> 4) & 3) * 8 + j;
    int n = (l & 15) + nt * 16;
    float v = 0.f;
    if (k < 144) {
      int kykx = k >> 4, ci = k & 15;
      int ky = kykx / 3, kx = kykx - ky * 3;
      v = c2w[((n * 16 + ci) * 3 + ky) * 3 + kx];
    }
    W2colF[i] = f2b(v);
  } else if (i < 56320) {               // WcatT[16][3200]
    int o = i - 5120;
    int r = o / 3200, d = o - r * 3200;
    float v = 0.f;
    if (r < 5) v = Wg[d * 5 + r];
    else if (r < 10) v = Wglu[d * 5 + (r - 5)];
    WcatT[o] = f2b(v);
  } else if (i < 138240) {              // W2T[e][g][h]
    int o = i - 56320;
    int e = o >> 14, rem = o & 16383;
    int g = rem >> 7, h = rem & 127;
    W2T[o] = f2b(W2e[(e * 128 + h) * 128 + g]);
  }
}

// ============ prep_w1t: tiled transpose W1e[e][d][h] -> W1T[e][h][d] bf16 ============
__global__ __launch_bounds__(256) void prep_w1t_kernel(
    const float* __restrict__ W1e, u16* __restrict__ W1T) {
  __shared__ float ts[64][129];
  int t = threadIdx.x;
  int e = blockIdx.x / 50, dt = blockIdx.x % 50;   // 64-row d tile
  {
    int d = t >> 2, hq = t & 3;
    const float* src = W1e + ((size_t)(e * 3200 + dt * 64 + d)) * 128;
#pragma unroll
    for (int u = 0; u < 8; u++) {
      int h4 = (hq + u * 4) * 4;
      float4 v = *(const float4*)(src + h4);
      ts[d][h4] = v.x; ts[d][h4 + 1] = v.y; ts[d][h4 + 2] = v.z; ts[d][h4 + 3] = v.w;
    }
  }
  __syncthreads();
  {
    int h = t >> 1, dh = t & 1;
    u16* dst = W1T + (size_t)e * 409600 + (size_t)h * 3200 + dt * 64 + dh * 32;
    uint32_t* dst32 = (uint32_t*)dst;
#pragma unroll
    for (int k = 0; k < 16; k++) {
      int d = dh * 32 + 2 * k;
      uint32_t lo = f2b(ts[d][h]), hi = f2b(ts[d + 1][h]);
      dst32[k] = lo | (hi << 16);
    }
  }
}

// ============ conv1 + relu + maxpool2 -> h1 bf16 HWC ============
__global__ __launch_bounds__(192) void conv1_kernel(
    const float* __restrict__ x, const float* __restrict__ w1,
    const float* __restrict__ b1, u16* __restrict__ h1) {
  __shared__ float xs[784];
  __shared__ float wsh[400];
  __shared__ float bsh[16];
  int t = threadIdx.x, b = blockIdx.x;
  const float4* xg = (const float4*)(x + (size_t)b * 784);
  float4* xs4 = (float4*)xs;
  for (int i = t; i < 196; i += 192) xs4[i] = xg[i];
  for (int i = t; i < 400; i += 192) wsh[i] = w1[i];
  if (t < 16) bsh[t] = b1[t];
  __syncthreads();
  int oc = t & 15, q0 = t >> 4;
  float w[25];
#pragma unroll
  for (int k = 0; k < 25; k++) w[k] = wsh[oc * 25 + k];
  float bias = bsh[oc];
  u16* out = h1 + (size_t)b * 2304;
#pragma unroll
  for (int it = 0; it < 6; it++) {
    int q = q0 + 12 * it;           // 0..71
    int py = q / 6, px2 = q - py * 6;
    int y0 = 2 * py, x0 = 4 * px2;
    float win[6][8];
#pragma unroll
    for (int r = 0; r < 6; r++) {
      const float4* p = (const float4*)&xs[(y0 + r) * 28 + x0];
      float4 a = p[0], c = p[1];
      win[r][0] = a.x; win[r][1] = a.y; win[r][2] = a.z; win[r][3] = a.w;
      win[r][4] = c.x; win[r][5] = c.y; win[r][6] = c.z; win[r][7] = c.w;
    }
#pragma unroll
    for (int half = 0; half < 2; half++) {
      int dxb = 2 * half;
      float c00 = 0.f, c01 = 0.f, c10 = 0.f, c11 = 0.f;
#pragma unroll
      for (int ky = 0; ky < 5; ky++)
#pragma unroll
        for (int kx = 0; kx < 5; kx++) {
          float wv = w[ky * 5 + kx];
          c00 += wv * win[ky][dxb + kx];
          c01 += wv * win[ky][dxb + kx + 1];
          c10 += wv * win[ky + 1][dxb + kx];
          c11 += wv * win[ky + 1][dxb + kx + 1];
        }
      float m = fmaxf(fmaxf(c00, c01), fmaxf(c10, c11)) + bias;
      m = fmaxf(m, 0.f);
      int px = 2 * px2 + half;
      out[(py * 12 + px) * 16 + oc] = f2b(m);
    }
  }
}

// ============ conv2 implicit-GEMM MFMA -> feat bf16 [B][3200] ============
__global__ __launch_bounds__(256) void conv2_kernel(
    const u16* __restrict__ h1, const u16* __restrict__ W2colF,
    const float* __restrict__ b2, u16* __restrict__ feat) {
  int t = threadIdx.x;
  int w = t >> 6, l = t & 63;
  bf16x8 bfr[5][2];
#pragma unroll
  for (int s = 0; s < 5; s++)
#pragma unroll
    for (int nt = 0; nt < 2; nt++)
      bfr[s][nt] = *(const bf16x8*)(W2colF + ((size_t)(s * 2 + nt) * 64 + l) * 8);
  int lm = l & 15, lq = l >> 4, hi = l >> 5;
  int cib = (lq & 1) * 8;
  int g0 = blockIdx.x * 128 + w * 32;
#pragma unroll
  for (int sub = 0; sub < 2; sub++) {
    int g = g0 + sub * 16 + lm;
    uint32_t bimg = (uint32_t)(((uint64_t)(uint32_t)g * 1374389535ull) >> 37);  // g/100
    int p = g - (int)bimg * 100;
    int y = (p * 205) >> 11;          // p/10
    int xc = p - y * 10;
    const u16* base = h1 + (size_t)bimg * 2304;
    f32x4 acc0 = {0.f, 0.f, 0.f, 0.f}, acc1 = {0.f, 0.f, 0.f, 0.f};
#pragma unroll
    for (int s = 0; s < 5; s++) {
      int kk = 2 * s + hi;
      if (kk > 8) kk = 8;            // pad lanes: B-frag rows there are zero
      int ky = (kk * 11) >> 5;       // kk/3 for kk<=8
      int kx = kk - ky * 3;
      int off = ((y + ky) * 12 + (xc + kx)) * 16 + cib;
      bf16x8 a = *(const bf16x8*)(base + off);
      acc0 = MFMA16(a, bfr[s][0], acc0);
      acc1 = MFMA16(a, bfr[s][1], acc1);
    }
#pragma unroll
    for (int nt = 0; nt < 2; nt++) {
      int n = lm + nt * 16;
      float bias = b2[n];
      f32x4 acc = nt ? acc1 : acc0;
#pragma unroll
      for (int rr = 0; rr < 4; rr++) {
        int gg = g0 + sub * 16 + lq * 4 + rr;
        uint32_t bi2 = (uint32_t)(((uint64_t)(uint32_t)gg * 1374389535ull) >> 37);
        int pp = gg - (int)bi2 * 100;
        float v = fmaxf(acc[rr] + bias, 0.f);
        feat[(size_t)bi2 * 3200 + n * 100 + pp] = f2b(v);
      }
    }
  }
}

// ============ router: split-K GLU gates + top3 softmax -> rw[B][5] ============
__global__ __launch_bounds__(256) void router_kernel(
    const u16* __restrict__ feat, const u16* __restrict__ WcatT,
    const float* __restrict__ bg, const float* __restrict__ bglu,
    float* __restrict__ rw) {
  __shared__ float part[4][16][16];
  int t = threadIdx.x, w = t >> 6, l = t & 63;
  int lm = l & 15, lq = l >> 4;
  int rg = w & 1, kh2 = w >> 1;
  int r0 = blockIdx.x * 32;
  const u16* arow = feat + (size_t)(r0 + rg * 16 + lm) * 3200 + kh2 * 1600 + lq * 8;
  const u16* brow = WcatT + (size_t)lm * 3200 + kh2 * 1600 + lq * 8;
  f32x4 acc = {0.f, 0.f, 0.f, 0.f};
#pragma unroll 5
  for (int s = 0; s < 50; s++) {
    bf16x8 a = *(const bf16x8*)arow;  arow += 32;
    bf16x8 bb = *(const bf16x8*)brow; brow += 32;
    acc = MFMA16(a, bb, acc);
  }
#pragma unroll
  for (int rr = 0; rr < 4; rr++) part[w][lq * 4 + rr][lm] = acc[rr];
  __syncthreads();
  if (t < 32) {
    int row = t & 15, g = t >> 4;
    int b = r0 + g * 16 + row;
    float gt[5];
#pragma unroll
    for (int e = 0; e < 5; e++) {
      float va = part[g][row][e] + part[g + 2][row][e] + bg[e];
      float vb = part[g][row][5 + e] + part[g + 2][row][5 + e] + bglu[e];
      gt[e] = va * (1.f / (1.f + __expf(-vb)));
    }
    float w3[3]; int i3[3];
    unsigned used = 0;
#pragma unroll
    for (int k = 0; k < 3; k++) {
      float best = -1e30f; int bi = 0;
#pragma unroll
      for (int e = 0; e < 5; e++)
        if (!((used >> e) & 1u) && gt[e] > best) { best = gt[e]; bi = e; }
      used |= 1u << bi; w3[k] = best; i3[k] = bi;
    }
    float s1 = __expf(w3[1] - w3[0]), s2 = __expf(w3[2] - w3[0]);
    float inv = 1.f / (1.f + s1 + s2);
    float o[5] = {0.f, 0.f, 0.f, 0.f, 0.f};
    o[i3[0]] = inv; o[i3[1]] = s1 * inv; o[i3[2]] = s2 * inv;
#pragma unroll
    for (int e = 0; e < 5; e++) rw[b * 5 + e] = o[e];
  }
}

// ============ gemm1: split-K expert layer-1, atomic fp32 accumulate ============
// grid 640: blk = mt + 64*e + 320*kh   (mt-major => feat tile pinned to one XCD)
__global__ __launch_bounds__(256, 3) void gemm1_kernel(
    const u16* __restrict__ feat, const u16* __restrict__ W1T,
    float* __restrict__ e1acc) {
  __shared__ u16 sA[2][4096];   // [buf][128 rows][32 cols swizzled]
  __shared__ u16 sB[2][4096];
  int t = threadIdx.x, w = t >> 6, l = t & 63;
  int blk = blockIdx.x;
  int mt = blk & 63;
  int e = (blk >> 6) % 5;
  int kh = blk / 320;
  size_t m0 = (size_t)mt * 128;
  int lm = l & 15, lq = l >> 4;
  int m_off = (w & 1) * 64, n_off = (w >> 1) * 64;
  int sw = ((lm ^ (lm >> 2)) & 3);
  int cs = (lq ^ sw) * 8;                 // u16 offset of lane's swizzled chunk

  // staging source pointers (swizzled column chunk)
  int r = t >> 2, bq = t & 3;
  int c = bq ^ ((r ^ (r >> 2)) & 3);
  const u16* pA0 = feat + (m0 + r) * 3200 + kh * 1600 + c * 8;
  const u16* pA1 = pA0 + 64 * 3200;
  const u16* pB0 = W1T + (size_t)e * 409600 + (size_t)r * 3200 + kh * 1600 + c * 8;
  const u16* pB1 = pB0 + 64 * 3200;
  u16* aL = &sA[0][w * 512];              // wave-uniform; HW adds lane*16B
  u16* bL = &sB[0][w * 512];

  f32x4 acc[4][4] = {};

  // prologue: stage s=0 into buf0
  GLD16(pA0, aL); GLD16(pA1, aL + 2048);
  GLD16(pB0, bL); GLD16(pB1, bL + 2048);
  pA0 += 32; pA1 += 32; pB0 += 32; pB1 += 32;

  for (int s = 0; s < 50; s++) {
    int buf = s & 1;
    if (s < 49) {
      u16* aN = &sA[buf ^ 1][w * 512];
      u16* bN = &sB[buf ^ 1][w * 512];
      GLD16(pA0, aN); GLD16(pA1, aN + 2048);
      GLD16(pB0, bN); GLD16(pB1, bN + 2048);
      pA0 += 32; pA1 += 32; pB0 += 32; pB1 += 32;
      asm volatile("s_waitcnt vmcnt(4)" ::: "memory");   // buf s complete; prefetch in flight
    } else {
      asm volatile("s_waitcnt vmcnt(0)" ::: "memory");
    }
    asm volatile("s_barrier" ::: "memory");
    const u16* A = sA[buf];
    const u16* B = sB[buf];
    bf16x8 af[4], bf[4];
#pragma unroll
    for (int i = 0; i < 4; i++) {
      af[i] = *(const bf16x8*)(A + (m_off + 16 * i + lm) * 32 + cs);
      bf[i] = *(const bf16x8*)(B + (n_off + 16 * i + lm) * 32 + cs);
    }
#pragma unroll
    for (int i = 0; i < 4; i++)
#pragma unroll
      for (int j = 0; j < 4; j++)
        acc[i][j] = MFMA16(af[i], bf[j], acc[i][j]);
    asm volatile("s_barrier" ::: "memory");   // guard buf reuse by next prefetch
  }
#pragma unroll
  for (int i = 0; i < 4; i++)
#pragma unroll
    for (int j = 0; j < 4; j++)
#pragma unroll
      for (int rr = 0; rr < 4; rr++) {
        int row = m_off + 16 * i + lq * 4 + rr;
        int col = n_off + 16 * j + lm;
        atomicAdd(&e1acc[(m0 + row) * 640 + e * 128 + col], acc[i][j][rr]);
      }
}

// ============ gemm2+combine+head: tanh(e1)@W2 -> tanh -> weighted sum -> Ws -> softmax ============
__global__ __launch_bounds__(256) void gemm2_head_kernel(
    const float* __restrict__ e1acc, const u16* __restrict__ W2T,
    const float* __restrict__ b1cat, const float* __restrict__ b2e,
    const float* __restrict__ rw, const float* __restrict__ Ws,
    const float* __restrict__ bs, float* __restrict__ out) {
  __shared__ u16 E1s[32][648];        // 41472 B; later overlaid by moes/parts
  __shared__ float wssh[1280];
  __shared__ float rws[160];
  int t = threadIdx.x;
  int r0 = blockIdx.x * 32;
  {
    int row = t >> 3;
    const float* src = e1acc + (size_t)(r0 + row) * 640;
#pragma unroll
    for (int k = 0; k < 20; k++) {
      int cb = (t & 7) + 8 * k;       // 0..159 chunks of 4
      float4 v = *(const float4*)(src + cb * 4);
      float4 bv = *(const float4*)(b1cat + cb * 4);
      u16 q0 = f2b(tanhfast(v.x + bv.x)), q1 = f2b(tanhfast(v.y + bv.y));
      u16 q2 = f2b(tanhfast(v.z + bv.z)), q3 = f2b(tanhfast(v.w + bv.w));
      uint32_t lo = q0 | ((uint32_t)q1 << 16), hi = q2 | ((uint32_t)q3 << 16);
      uint32_t* dst = (uint32_t*)&E1s[row][cb * 4];
      dst[0] = lo; dst[1] = hi;
    }
  }
  if (t < 160) rws[t] = rw[r0 * 5 + t];
  for (int i = t; i < 1280; i += 256) wssh[i] = Ws[i];
  __syncthreads();

  int w = t >> 6, l = t & 63, lm = l & 15, lq = l >> 4;
  int mh = w & 1, nh = w >> 1;
  f32x4 moeacc[4] = {};
#pragma unroll
  for (int e = 0; e < 5; e++) {
    f32x4 acc[4] = {};
    const u16* w2e = W2T + e * 16384;
#pragma unroll
    for (int kk = 0; kk < 4; kk++) {
      bf16x8 a = *(const bf16x8*)&E1s[mh * 16 + lm][e * 128 + kk * 32 + lq * 8];
#pragma unroll
      for (int j = 0; j < 4; j++) {
        bf16x8 b = *(const bf16x8*)(w2e + (nh * 64 + 16 * j + lm) * 128 + kk * 32 + lq * 8);
        acc[j] = MFMA16(a, b, acc[j]);
      }
    }
#pragma unroll
    for (int j = 0; j < 4; j++) {
      float b2v = b2e[e * 128 + nh * 64 + 16 * j + lm];
#pragma unroll
      for (int rr = 0; rr < 4; rr++) {
        float v = tanhfast(acc[j][rr] + b2v);
        moeacc[j][rr] += rws[(mh * 16 + lq * 4 + rr) * 5 + e] * v;
      }
    }
  }
  __syncthreads();                     // done reading E1s
  float* moes = (float*)&E1s[0][0];    // [32][132]
#pragma unroll
  for (int j = 0; j < 4; j++)
#pragma unroll
    for (int rr = 0; rr < 4; rr++)
      moes[(mh * 16 + lq * 4 + rr) * 132 + nh * 64 + 16 * j + lm] = moeacc[j][rr];
  __syncthreads();
  float* parts = moes + 32 * 132;      // [32][4][10]
  if (t < 128) {
    int row = t >> 2, qc = t & 3;
    float pl[10] = {};
    for (int cc = qc * 32; cc < qc * 32 + 32; cc++) {
      float mv = moes[row * 132 + cc];
#pragma unroll
      for (int cls = 0; cls < 10; cls++) pl[cls] += mv * wssh[cc * 10 + cls];
    }
#pragma unroll
    for (int cls = 0; cls < 10; cls++) parts[(row * 4 + qc) * 10 + cls] = pl[cls];
  }
  __syncthreads();
  if (t < 32) {
    float lg[10];
    float mx = -1e30f;
#pragma unroll
    for (int cls = 0; cls < 10; cls++) {
      lg[cls] = parts[(t * 4) * 10 + cls] + parts[(t * 4 + 1) * 10 + cls] +
                parts[(t * 4 + 2) * 10 + cls] + parts[(t * 4 + 3) * 10 + cls] + bs[cls];
      mx = fmaxf(mx, lg[cls]);
    }
    float sum = 0.f;
#pragma unroll
    for (int cls = 0; cls < 10; cls++) { lg[cls] = __expf(lg[cls] - mx); sum += lg[cls]; }
    float inv = 1.f / sum;
    float* orow = out + (size_t)(r0 + t) * 10;
#pragma unroll
    for (int cls = 0; cls < 10; cls++) orow[cls] = lg[cls] * inv;
  }
}

extern "C" void kernel_launch(void* const* d_in, const int* in_sizes, int n_in,
                              void* d_out, int out_size, void* d_ws, size_t ws_size,
                              hipStream_t stream) {
  const float* x    = (const float*)d_in[0];
  const float* c1w  = (const float*)d_in[1];
  const float* c1b  = (const float*)d_in[2];
  const float* c2w  = (const float*)d_in[3];
  const float* c2b  = (const float*)d_in[4];
  const float* Wg   = (const float*)d_in[5];
  const float* bg   = (const float*)d_in[6];
  const float* Wglu = (const float*)d_in[7];
  const float* bglu = (const float*)d_in[8];
  const float* W1e  = (const float*)d_in[9];
  const float* b1e  = (const float*)d_in[10];
  const float* W2e  = (const float*)d_in[11];
  const float* b2e  = (const float*)d_in[12];
  const float* Wsp  = (const float*)d_in[13];
  const float* bsp  = (const float*)d_in[14];
  char* ws = (char*)d_ws;
  u16* h1      = (u16*)(ws + 0);
  float* e1acc = (float*)(ws + 0);          // overlays h1 (dead after conv2)
  u16* feat    = (u16*)(ws + 37748736);
  u16* W1T     = (u16*)(ws + 90177536);
  u16* W2T     = (u16*)(ws + 94273536);
  u16* W2colF  = (u16*)(ws + 94437376);
  u16* WcatT   = (u16*)(ws + 94447616);
  float* rw    = (float*)(ws + 94550016);

  prep_misc_kernel<<<540, 256, 0, stream>>>(c2w, Wg, Wglu, W2e, W2colF, WcatT, W2T);
  prep_w1t_kernel<<<250, 256, 0, stream>>>(W1e, W1T);
  conv1_kernel<<<8192, 192, 0, stream>>>(x, c1w, c1b, h1);
  conv2_kernel<<<6400, 256, 0, stream>>>(h1, W2colF, c2b, feat);
  router_kernel<<<256, 256, 0, stream>>>(feat, WcatT, bg, bglu, rw);
  hipMemsetAsync(e1acc, 0, (size_t)8192 * 640 * 4, stream);   // h1 dead now
  gemm1_kernel<<<640, 256, 0, stream>>>(feat, W1T, e1acc);
  gemm2_head_kernel<<<256, 256, 0, stream>>>(e1acc, W2T, b1e, b2e, rw, Wsp, bsp,
                                             (float*)d_out);
}

// Round 3
// 281.956 us; speedup vs baseline: 1.1432x; 1.0868x over previous
//
#include <hip/hip_runtime.h>
#include <stdint.h>

typedef unsigned short u16;
typedef __attribute__((ext_vector_type(8))) short bf16x8;   // 8 bf16 = 4 VGPRs
typedef __attribute__((ext_vector_type(4))) float f32x4;

#define MFMA16(a, b, c) __builtin_amdgcn_mfma_f32_16x16x32_bf16((a), (b), (c), 0, 0, 0)
#define GLD16(gp, lp) __builtin_amdgcn_global_load_lds( \
    (__attribute__((address_space(1))) void*)(gp), \
    (__attribute__((address_space(3))) void*)(lp), 16, 0, 0)

__device__ __forceinline__ u16 f2b(float f) {   // fp32 -> bf16 RNE
  uint32_t u = __float_as_uint(f);
  u += 0x7FFFu + ((u >> 16) & 1u);
  return (u16)(u >> 16);
}
__device__ __forceinline__ float tanhfast(float x) {
  float e = __expf(2.f * x);
  return (e - 1.f) / (e + 1.f);
}

// ---------------- workspace layout (bytes) ----------------
// region0: h1 bf16 [8192][12][12][16]  @ 0         37,748,736
//          e1b bf16 [8192][640] overlays region0 (h1 dead after conv2)
// feat bf16 [8192][3200]            @ 37748736   52,428,800
// W1T bf16 [5][128][3200]           @ 90177536    4,096,000
// W2T bf16 [5][128][128]            @ 94273536      163,840
// W2colF bf16 [5][2][64][8]         @ 94437376       10,240
// WcatT bf16 [16][3200]             @ 94447616      102,400
// rw f32 [8192][5]                  @ 94550016      163,840   (total 94.7 MB)

// ============ prep_misc: small weight repacks ============
__global__ __launch_bounds__(256) void prep_misc_kernel(
    const float* __restrict__ c2w, const float* __restrict__ Wg,
    const float* __restrict__ Wglu, const float* __restrict__ W2e,
    u16* __restrict__ W2colF, u16* __restrict__ WcatT, u16* __restrict__ W2T) {
  int i = blockIdx.x * 256 + threadIdx.x;
  if (i < 5120) {                       // conv2 B-fragments, k=(ky*3+kx)*16+ci, pad->160
    int j = i & 7, l = (i >> 3) & 63, nt = (i >> 9) & 1, s = i >> 10;
    int k = s * 32 + ((l >> 4) & 3) * 8 + j;
    int n = (l & 15) + nt * 16;
    float v = 0.f;
    if (k < 144) {
      int kykx = k >> 4, ci = k & 15;
      int ky = kykx / 3, kx = kykx - ky * 3;
      v = c2w[((n * 16 + ci) * 3 + ky) * 3 + kx];
    }
    W2colF[i] = f2b(v);
  } else if (i < 56320) {               // WcatT[16][3200]
    int o = i - 5120;
    int r = o / 3200, d = o - r * 3200;
    float v = 0.f;
    if (r < 5) v = Wg[d * 5 + r];
    else if (r < 10) v = Wglu[d * 5 + (r - 5)];
    WcatT[o] = f2b(v);
  } else if (i < 138240) {              // W2T[e][g][h]
    int o = i - 56320;
    int e = o >> 14, rem = o & 16383;
    int g = rem >> 7, h = rem & 127;
    W2T[o] = f2b(W2e[(e * 128 + h) * 128 + g]);
  }
}

// ============ prep_w1t: tiled transpose W1e[e][d][h] -> W1T[e][h][d] bf16 ============
__global__ __launch_bounds__(256) void prep_w1t_kernel(
    const float* __restrict__ W1e, u16* __restrict__ W1T) {
  __shared__ float ts[64][129];
  int t = threadIdx.x;
  int e = blockIdx.x / 50, dt = blockIdx.x % 50;   // 64-row d tile
  {
    int d = t >> 2, hq = t & 3;
    const float* src = W1e + ((size_t)(e * 3200 + dt * 64 + d)) * 128;
#pragma unroll
    for (int u = 0; u < 8; u++) {
      int h4 = (hq + u * 4) * 4;
      float4 v = *(const float4*)(src + h4);
      ts[d][h4] = v.x; ts[d][h4 + 1] = v.y; ts[d][h4 + 2] = v.z; ts[d][h4 + 3] = v.w;
    }
  }
  __syncthreads();
  {
    int h = t >> 1, dh = t & 1;
    u16* dst = W1T + (size_t)e * 409600 + (size_t)h * 3200 + dt * 64 + dh * 32;
    uint32_t* dst32 = (uint32_t*)dst;
#pragma unroll
    for (int k = 0; k < 16; k++) {
      int d = dh * 32 + 2 * k;
      uint32_t lo = f2b(ts[d][h]), hi = f2b(ts[d + 1][h]);
      dst32[k] = lo | (hi << 16);
    }
  }
}

// ============ conv1 + relu + maxpool2 -> h1 bf16 HWC ============
__global__ __launch_bounds__(192) void conv1_kernel(
    const float* __restrict__ x, const float* __restrict__ w1,
    const float* __restrict__ b1, u16* __restrict__ h1) {
  __shared__ float xs[784];
  __shared__ float wsh[400];
  __shared__ float bsh[16];
  int t = threadIdx.x, b = blockIdx.x;
  const float4* xg = (const float4*)(x + (size_t)b * 784);
  float4* xs4 = (float4*)xs;
  for (int i = t; i < 196; i += 192) xs4[i] = xg[i];
  for (int i = t; i < 400; i += 192) wsh[i] = w1[i];
  if (t < 16) bsh[t] = b1[t];
  __syncthreads();
  int oc = t & 15, q0 = t >> 4;
  float w[25];
#pragma unroll
  for (int k = 0; k < 25; k++) w[k] = wsh[oc * 25 + k];
  float bias = bsh[oc];
  u16* out = h1 + (size_t)b * 2304;
#pragma unroll
  for (int it = 0; it < 6; it++) {
    int q = q0 + 12 * it;           // 0..71
    int py = q / 6, px2 = q - py * 6;
    int y0 = 2 * py, x0 = 4 * px2;
    float win[6][8];
#pragma unroll
    for (int r = 0; r < 6; r++) {
      const float4* p = (const float4*)&xs[(y0 + r) * 28 + x0];
      float4 a = p[0], c = p[1];
      win[r][0] = a.x; win[r][1] = a.y; win[r][2] = a.z; win[r][3] = a.w;
      win[r][4] = c.x; win[r][5] = c.y; win[r][6] = c.z; win[r][7] = c.w;
    }
#pragma unroll
    for (int half = 0; half < 2; half++) {
      int dxb = 2 * half;
      float c00 = 0.f, c01 = 0.f, c10 = 0.f, c11 = 0.f;
#pragma unroll
      for (int ky = 0; ky < 5; ky++)
#pragma unroll
        for (int kx = 0; kx < 5; kx++) {
          float wv = w[ky * 5 + kx];
          c00 += wv * win[ky][dxb + kx];
          c01 += wv * win[ky][dxb + kx + 1];
          c10 += wv * win[ky + 1][dxb + kx];
          c11 += wv * win[ky + 1][dxb + kx + 1];
        }
      float m = fmaxf(fmaxf(c00, c01), fmaxf(c10, c11)) + bias;
      m = fmaxf(m, 0.f);
      int px = 2 * px2 + half;
      out[(py * 12 + px) * 16 + oc] = f2b(m);
    }
  }
}

// ============ conv2 implicit-GEMM MFMA -> feat bf16 [B][3200] ============
__global__ __launch_bounds__(256) void conv2_kernel(
    const u16* __restrict__ h1, const u16* __restrict__ W2colF,
    const float* __restrict__ b2, u16* __restrict__ feat) {
  int t = threadIdx.x;
  int w = t >> 6, l = t & 63;
  bf16x8 bfr[5][2];
#pragma unroll
  for (int s = 0; s < 5; s++)
#pragma unroll
    for (int nt = 0; nt < 2; nt++)
      bfr[s][nt] = *(const bf16x8*)(W2colF + ((size_t)(s * 2 + nt) * 64 + l) * 8);
  int lm = l & 15, lq = l >> 4, hi = l >> 5;
  int cib = (lq & 1) * 8;
  int g0 = blockIdx.x * 128 + w * 32;
#pragma unroll
  for (int sub = 0; sub < 2; sub++) {
    int g = g0 + sub * 16 + lm;
    uint32_t bimg = (uint32_t)(((uint64_t)(uint32_t)g * 1374389535ull) >> 37);  // g/100
    int p = g - (int)bimg * 100;
    int y = (p * 205) >> 11;          // p/10
    int xc = p - y * 10;
    const u16* base = h1 + (size_t)bimg * 2304;
    f32x4 acc0 = {0.f, 0.f, 0.f, 0.f}, acc1 = {0.f, 0.f, 0.f, 0.f};
#pragma unroll
    for (int s = 0; s < 5; s++) {
      int kk = 2 * s + hi;
      if (kk > 8) kk = 8;            // pad lanes: B-frag rows there are zero
      int ky = (kk * 11) >> 5;       // kk/3 for kk<=8
      int kx = kk - ky * 3;
      int off = ((y + ky) * 12 + (xc + kx)) * 16 + cib;
      bf16x8 a = *(const bf16x8*)(base + off);
      acc0 = MFMA16(a, bfr[s][0], acc0);
      acc1 = MFMA16(a, bfr[s][1], acc1);
    }
#pragma unroll
    for (int nt = 0; nt < 2; nt++) {
      int n = lm + nt * 16;
      float bias = b2[n];
      f32x4 acc = nt ? acc1 : acc0;
#pragma unroll
      for (int rr = 0; rr < 4; rr++) {
        int gg = g0 + sub * 16 + lq * 4 + rr;
        uint32_t bi2 = (uint32_t)(((uint64_t)(uint32_t)gg * 1374389535ull) >> 37);
        int pp = gg - (int)bi2 * 100;
        float v = fmaxf(acc[rr] + bias, 0.f);
        feat[(size_t)bi2 * 3200 + n * 100 + pp] = f2b(v);
      }
    }
  }
}

// ============ gemm1: 64x128 tile, depth-3 pipeline, fused tanh + router ============
// grid 640: blk = mt + 128*e.  Output e1b = tanh(feat@W1e + b1) bf16 [8192][640].
// e==0 blocks also compute router gates (WcatT staged every block for uniform vmcnt).
__global__ __launch_bounds__(256, 3) void gemm1_kernel(
    const u16* __restrict__ feat, const u16* __restrict__ W1T,
    const u16* __restrict__ WcatT, const float* __restrict__ b1e,
    const float* __restrict__ bg, const float* __restrict__ bglu,
    u16* __restrict__ e1b, float* __restrict__ rw) {
  __shared__ u16 lds[26624];            // 4 stages x 6656 u16 (A 2048 | B 4096 | W 512)
  int t = threadIdx.x, w = t >> 6, l = t & 63;
  int mt = blockIdx.x & 127;
  int e = blockIdx.x >> 7;
  size_t m0 = (size_t)mt * 64;
  int lm = l & 15, lq = l >> 4;
  int m_off = (w & 1) * 32, n_off = (w >> 1) * 64;
  bool rwave = (e == 0) && (w < 2);

  const u16* pA = feat + (m0 + (t >> 2)) * 3200 + (t & 3) * 8;
  const u16* pB1 = W1T + (size_t)e * 409600 + (size_t)(t >> 2) * 3200 + (t & 3) * 8;
  const u16* pB2 = pB1 + 64 * 3200;
  const u16* pW = WcatT + (size_t)(l >> 2) * 3200 + (l & 3) * 8;

  f32x4 acc[2][4] = {};
  f32x4 racc[2] = {};

  // prologue: stage iters 0,1,2 into bufs 0,1,2 (4 loads/thread each)
#pragma unroll
  for (int p = 0; p < 3; p++) {
    u16* st = lds + p * 6656;
    GLD16(pA, st + w * 512);
    GLD16(pB1, st + 2048 + w * 512);
    GLD16(pB2, st + 4096 + w * 512);
    GLD16(pW, st + 6144);               // all waves dup-write same data (uniform vmcnt)
    pA += 32; pB1 += 32; pB2 += 32; pW += 32;
  }

  auto compute = [&](int buf) {
    const u16* st = lds + buf * 6656;
    bf16x8 af[2], bf[4];
#pragma unroll
    for (int i = 0; i < 2; i++)
      af[i] = *(const bf16x8*)(st + (m_off + 16 * i + lm) * 32 + lq * 8);
#pragma unroll
    for (int j = 0; j < 4; j++)
      bf[j] = *(const bf16x8*)(st + 2048 + (n_off + 16 * j + lm) * 32 + lq * 8);
#pragma unroll
    for (int i = 0; i < 2; i++)
#pragma unroll
      for (int j = 0; j < 4; j++)
        acc[i][j] = MFMA16(af[i], bf[j], acc[i][j]);
    if (rwave) {
      bf16x8 wf = *(const bf16x8*)(st + 6144 + lm * 32 + lq * 8);
      racc[0] = MFMA16(af[0], wf, racc[0]);
      racc[1] = MFMA16(af[1], wf, racc[1]);
    }
  };

  for (int s = 0; s < 97; s++) {
    asm volatile("s_waitcnt vmcnt(8)\n\ts_barrier" ::: "memory");  // stage s landed
    u16* st = lds + ((s + 3) & 3) * 6656;     // buf[(s-1)%4]: safe, barrier passed
    GLD16(pA, st + w * 512);
    GLD16(pB1, st + 2048 + w * 512);
    GLD16(pB2, st + 4096 + w * 512);
    GLD16(pW, st + 6144);
    pA += 32; pB1 += 32; pB2 += 32; pW += 32;
    compute(s & 3);
  }
  asm volatile("s_waitcnt vmcnt(8)\n\ts_barrier" ::: "memory");
  compute(1);                                  // s=97
  asm volatile("s_waitcnt vmcnt(4)\n\ts_barrier" ::: "memory");
  compute(2);                                  // s=98
  asm volatile("s_waitcnt vmcnt(0)\n\ts_barrier" ::: "memory");
  compute(3);                                  // s=99

  // epilogue: tanh+bias -> bf16, LDS transpose for vectorized stores
  float b1v[4];
#pragma unroll
  for (int j = 0; j < 4; j++) b1v[j] = b1e[e * 128 + n_off + 16 * j + lm];
  u16* E1t = lds;                              // [64][128] u16 (stage bufs dead)
#pragma unroll
  for (int i = 0; i < 2; i++)
#pragma unroll
    for (int j = 0; j < 4; j++)
#pragma unroll
      for (int rr = 0; rr < 4; rr++) {
        int row = m_off + 16 * i + lq * 4 + rr;
        int col = n_off + 16 * j + lm;
        E1t[row * 128 + col] = f2b(tanhfast(acc[i][j][rr] + b1v[j]));
      }
  if (rwave) {
    float* RACC = (float*)(lds + 16384);       // [64][16] f32 @ byte 32768
#pragma unroll
    for (int i = 0; i < 2; i++)
#pragma unroll
      for (int rr = 0; rr < 4; rr++)
        RACC[(m_off + 16 * i + lq * 4 + rr) * 16 + lm] = racc[i][rr];
  }
  __syncthreads();
#pragma unroll
  for (int k2 = 0; k2 < 4; k2++) {
    int u = t + k2 * 256;                      // 1024 segs of 16B
    int row = u >> 4, sc = u & 15;
    uint4 v = *(const uint4*)(E1t + row * 128 + sc * 8);
    *(uint4*)(e1b + (m0 + row) * 640 + e * 128 + sc * 8) = v;
  }
  if (e == 0 && t < 64) {
    const float* RACC = (const float*)(lds + 16384);
    float gt[5];
#pragma unroll
    for (int ee = 0; ee < 5; ee++) {
      float va = RACC[t * 16 + ee] + bg[ee];
      float vb = RACC[t * 16 + 5 + ee] + bglu[ee];
      gt[ee] = va * (1.f / (1.f + __expf(-vb)));
    }
    float w3[3]; int i3[3];
    unsigned used = 0;
#pragma unroll
    for (int k = 0; k < 3; k++) {
      float best = -1e30f; int bi = 0;
#pragma unroll
      for (int ee = 0; ee < 5; ee++)
        if (!((used >> ee) & 1u) && gt[ee] > best) { best = gt[ee]; bi = ee; }
      used |= 1u << bi; w3[k] = best; i3[k] = bi;
    }
    float s1 = __expf(w3[1] - w3[0]), s2 = __expf(w3[2] - w3[0]);
    float inv = 1.f / (1.f + s1 + s2);
    float o[5] = {0.f, 0.f, 0.f, 0.f, 0.f};
    o[i3[0]] = inv; o[i3[1]] = s1 * inv; o[i3[2]] = s2 * inv;
#pragma unroll
    for (int ee = 0; ee < 5; ee++) rw[(m0 + t) * 5 + ee] = o[ee];
  }
}

// ============ gemm2+combine+head: e1b@W2 -> tanh -> weighted sum -> Ws -> softmax ============
__global__ __launch_bounds__(256) void gemm2_head_kernel(
    const u16* __restrict__ e1b, const u16* __restrict__ W2T,
    const float* __restrict__ b2e, const float* __restrict__ rw,
    const float* __restrict__ Ws, const float* __restrict__ bs,
    float* __restrict__ out) {
  __shared__ u16 E1s[32][648];        // later overlaid by moes/parts
  __shared__ float wssh[1280];
  __shared__ float rws[160];
  int t = threadIdx.x;
  int r0 = blockIdx.x * 32;
  {
    int row = t >> 3;
    const u16* src = e1b + (size_t)(r0 + row) * 640 + (t & 7) * 8;
    u16* drow = &E1s[row][(t & 7) * 8];
#pragma unroll
    for (int k = 0; k < 10; k++)
      *(uint4*)(drow + k * 64) = *(const uint4*)(src + k * 64);
  }
  if (t < 160) rws[t] = rw[r0 * 5 + t];
  for (int i = t; i < 1280; i += 256) wssh[i] = Ws[i];
  __syncthreads();

  int w = t >> 6, l = t & 63, lm = l & 15, lq = l >> 4;
  int mh = w & 1, nh = w >> 1;
  f32x4 moeacc[4] = {};
#pragma unroll
  for (int e = 0; e < 5; e++) {
    f32x4 acc[4] = {};
    const u16* w2e = W2T + e * 16384;
#pragma unroll
    for (int kk = 0; kk < 4; kk++) {
      bf16x8 a = *(const bf16x8*)&E1s[mh * 16 + lm][e * 128 + kk * 32 + lq * 8];
#pragma unroll
      for (int j = 0; j < 4; j++) {
        bf16x8 b = *(const bf16x8*)(w2e + (nh * 64 + 16 * j + lm) * 128 + kk * 32 + lq * 8);
        acc[j] = MFMA16(a, b, acc[j]);
      }
    }
#pragma unroll
    for (int j = 0; j < 4; j++) {
      float b2v = b2e[e * 128 + nh * 64 + 16 * j + lm];
#pragma unroll
      for (int rr = 0; rr < 4; rr++) {
        float v = tanhfast(acc[j][rr] + b2v);
        moeacc[j][rr] += rws[(mh * 16 + lq * 4 + rr) * 5 + e] * v;
      }
    }
  }
  __syncthreads();                     // done reading E1s
  float* moes = (float*)&E1s[0][0];    // [32][132]
#pragma unroll
  for (int j = 0; j < 4; j++)
#pragma unroll
    for (int rr = 0; rr < 4; rr++)
      moes[(mh * 16 + lq * 4 + rr) * 132 + nh * 64 + 16 * j + lm] = moeacc[j][rr];
  __syncthreads();
  float* parts = moes + 32 * 132;      // [32][4][10]
  if (t < 128) {
    int row = t >> 2, qc = t & 3;
    float pl[10] = {};
    for (int cc = qc * 32; cc < qc * 32 + 32; cc++) {
      float mv = moes[row * 132 + cc];
#pragma unroll
      for (int cls = 0; cls < 10; cls++) pl[cls] += mv * wssh[cc * 10 + cls];
    }
#pragma unroll
    for (int cls = 0; cls < 10; cls++) parts[(row * 4 + qc) * 10 + cls] = pl[cls];
  }
  __syncthreads();
  if (t < 32) {
    float lg[10];
    float mx = -1e30f;
#pragma unroll
    for (int cls = 0; cls < 10; cls++) {
      lg[cls] = parts[(t * 4) * 10 + cls] + parts[(t * 4 + 1) * 10 + cls] +
                parts[(t * 4 + 2) * 10 + cls] + parts[(t * 4 + 3) * 10 + cls] + bs[cls];
      mx = fmaxf(mx, lg[cls]);
    }
    float sum = 0.f;
#pragma unroll
    for (int cls = 0; cls < 10; cls++) { lg[cls] = __expf(lg[cls] - mx); sum += lg[cls]; }
    float inv = 1.f / sum;
    float* orow = out + (size_t)(r0 + t) * 10;
#pragma unroll
    for (int cls = 0; cls < 10; cls++) orow[cls] = lg[cls] * inv;
  }
}

extern "C" void kernel_launch(void* const* d_in, const int* in_sizes, int n_in,
                              void* d_out, int out_size, void* d_ws, size_t ws_size,
                              hipStream_t stream) {
  const float* x    = (const float*)d_in[0];
  const float* c1w  = (const float*)d_in[1];
  const float* c1b  = (const float*)d_in[2];
  const float* c2w  = (const float*)d_in[3];
  const float* c2b  = (const float*)d_in[4];
  const float* Wg   = (const float*)d_in[5];
  const float* bg   = (const float*)d_in[6];
  const float* Wglu = (const float*)d_in[7];
  const float* bglu = (const float*)d_in[8];
  const float* W1e  = (const float*)d_in[9];
  const float* b1e  = (const float*)d_in[10];
  const float* W2e  = (const float*)d_in[11];
  const float* b2e  = (const float*)d_in[12];
  const float* Wsp  = (const float*)d_in[13];
  const float* bsp  = (const float*)d_in[14];
  char* ws = (char*)d_ws;
  u16* h1      = (u16*)(ws + 0);
  u16* e1b     = (u16*)(ws + 0);            // overlays h1 (dead after conv2)
  u16* feat    = (u16*)(ws + 37748736);
  u16* W1T     = (u16*)(ws + 90177536);
  u16* W2T     = (u16*)(ws + 94273536);
  u16* W2colF  = (u16*)(ws + 94437376);
  u16* WcatT   = (u16*)(ws + 94447616);
  float* rw    = (float*)(ws + 94550016);

  prep_misc_kernel<<<540, 256, 0, stream>>>(c2w, Wg, Wglu, W2e, W2colF, WcatT, W2T);
  prep_w1t_kernel<<<250, 256, 0, stream>>>(W1e, W1T);
  conv1_kernel<<<8192, 192, 0, stream>>>(x, c1w, c1b, h1);
  conv2_kernel<<<6400, 256, 0, stream>>>(h1, W2colF, c2b, feat);
  gemm1_kernel<<<640, 256, 0, stream>>>(feat, W1T, WcatT, b1e, bg, bglu, e1b, rw);
  gemm2_head_kernel<<<256, 256, 0, stream>>>(e1b, W2T, b2e, rw, Wsp, bsp,
                                             (float*)d_out);
}